// Round 2
// baseline (805.697 us; speedup 1.0000x reference)
//
#include <hip/hip_runtime.h>
#include <hip/hip_bf16.h>

#define N_NODES  20000
#define N_EDGES  640000
#define E_TOT    (N_EDGES + N_NODES)
#define N_GRAPHS 64

typedef __hip_bfloat16 bf16;

__device__ __forceinline__ float b2f(bf16 v) { return __bfloat162float(v); }
__device__ __forceinline__ bf16  f2b(float v) { return __float2bfloat16(v); }

// dual-dtype loads: flags decided at runtime by k_detect (wave-uniform branch)
__device__ __forceinline__ float ldf(const void* p, int i, int f32) {
    return f32 ? ((const float*)p)[i] : b2f(((const bf16*)p)[i]);
}
__device__ __forceinline__ int ldi(const void* p, int i, int i64) {
    return i64 ? (int)((const long long*)p)[i] : ((const int*)p)[i];
}

// ---------------- dtype sniffing ----------------
// flags[0]=1 -> float inputs are f32 (else bf16). flags[1]=1 -> ints are int64.
__global__ void k_detect(const void* __restrict__ x, const void* __restrict__ ei,
                         int* __restrict__ flags) {
    if (threadIdx.x != 0 || blockIdx.x != 0) return;
    const bf16* xb = (const bf16*)x;
    int f32 = 0;
    for (int i = 0; i < 128; ++i) {
        float v = b2f(xb[i]);
        if (!(fabsf(v) < 1e6f)) f32 = 1;   // catches huge values and NaN
    }
    const int* e32 = (const int*)ei;
    int allzero = 1;
    for (int i = 0; i < 64; ++i) if (e32[2 * i + 1] != 0) allzero = 0;
    flags[0] = f32;
    flags[1] = allzero;
}

// ---------------- CSR build ----------------
__global__ void k_count(const void* __restrict__ ei, const int* __restrict__ flags,
                        int* __restrict__ cnt) {
    int e = blockIdx.x * blockDim.x + threadIdx.x;
    if (e >= E_TOT) return;
    int i64 = flags[1];
    int dst = (e < N_EDGES) ? ldi(ei, N_EDGES + e, i64) : (e - N_EDGES);
    atomicAdd(&cnt[dst], 1);
}

__global__ void k_scan(const int* __restrict__ cnt, int* __restrict__ off) {
    __shared__ int s[256];
    __shared__ int carry;
    if (threadIdx.x == 0) carry = 0;
    __syncthreads();
    for (int base = 0; base < N_NODES; base += 256) {
        int i = base + threadIdx.x;
        int v = (i < N_NODES) ? cnt[i] : 0;
        s[threadIdx.x] = v;
        __syncthreads();
        #pragma unroll
        for (int d = 1; d < 256; d <<= 1) {
            int t = (threadIdx.x >= d) ? s[threadIdx.x - d] : 0;
            __syncthreads();
            s[threadIdx.x] += t;
            __syncthreads();
        }
        if (i < N_NODES) off[i] = carry + s[threadIdx.x] - v;  // exclusive
        __syncthreads();
        if (threadIdx.x == 0) carry += s[255];
        __syncthreads();
    }
    if (threadIdx.x == 0) off[N_NODES] = carry;
}

__global__ void k_scatter(const void* __restrict__ ei, const int* __restrict__ flags,
                          const int* __restrict__ off,
                          int* __restrict__ cnt, int* __restrict__ csr_src) {
    int e = blockIdx.x * blockDim.x + threadIdx.x;
    if (e >= E_TOT) return;
    int i64 = flags[1];
    int src, dst;
    if (e < N_EDGES) { src = ldi(ei, e, i64); dst = ldi(ei, N_EDGES + e, i64); }
    else             { src = dst = e - N_EDGES; }
    int r = atomicSub(&cnt[dst], 1);           // old value: deg..1
    csr_src[off[dst] + r - 1] = src;
}

// ---------------- layer 1: x@W1 + attention logits ----------------
__global__ void k_gemm1(const void* __restrict__ x, const void* __restrict__ W1,
                        const void* __restrict__ a_src, const void* __restrict__ a_dst,
                        const int* __restrict__ flags,
                        bf16* __restrict__ xh, float* __restrict__ al) {
    int f32 = flags[0];
    __shared__ float xs[8][128];
    int tid = threadIdx.x;         // 128
    int row0 = blockIdx.x * 8;
    #pragma unroll
    for (int r = 0; r < 8; ++r) xs[r][tid] = ldf(x, (row0 + r) * 128 + tid, f32);
    __syncthreads();
    float acc[8] = {0.f,0.f,0.f,0.f,0.f,0.f,0.f,0.f};
    for (int k = 0; k < 128; ++k) {
        float w = ldf(W1, k * 128 + tid, f32);
        #pragma unroll
        for (int r = 0; r < 8; ++r) acc[r] += xs[r][k] * w;
    }
    float asv = ldf(a_src, tid, f32);
    float adv = ldf(a_dst, tid, f32);
    int head = tid >> 6;
    #pragma unroll
    for (int r = 0; r < 8; ++r) {
        int n = row0 + r;
        xh[n * 128 + tid] = f2b(acc[r]);
        float ps = acc[r] * asv;
        float pd = acc[r] * adv;
        #pragma unroll
        for (int d = 32; d > 0; d >>= 1) {
            ps += __shfl_down(ps, d);
            pd += __shfl_down(pd, d);
        }
        if ((tid & 63) == 0) {
            al[n * 4 + head]     = ps;   // [as0, as1, ad0, ad1]
            al[n * 4 + 2 + head] = pd;
        }
    }
}

// one wave per dst node, online softmax over CSR edge list
__global__ void k_agg1(const bf16* __restrict__ xh, const float* __restrict__ al,
                       const void* __restrict__ b1, const int* __restrict__ flags,
                       const int* __restrict__ off, const int* __restrict__ csr_src,
                       bf16* __restrict__ h1) {
    int f32 = flags[0];
    int node = blockIdx.x * 4 + threadIdx.y;
    if (node >= N_NODES) return;
    int lane = threadIdx.x;
    float ad0 = al[node * 4 + 2];
    float ad1 = al[node * 4 + 3];
    int s = off[node], e = off[node + 1];
    float m0 = -1e30f, m1 = -1e30f;
    float l0 = 0.f, l1 = 0.f, a0 = 0.f, a1 = 0.f;
    for (int k = s; k < e; ++k) {
        int src = csr_src[k];
        float e0 = al[src * 4 + 0] + ad0;
        float e1 = al[src * 4 + 1] + ad1;
        e0 = (e0 > 0.f) ? e0 : 0.2f * e0;   // leaky_relu(0.2)
        e1 = (e1 > 0.f) ? e1 : 0.2f * e1;
        float m0n = fmaxf(m0, e0), m1n = fmaxf(m1, e1);
        float sc0 = __expf(m0 - m0n), sc1 = __expf(m1 - m1n);
        float p0  = __expf(e0 - m0n), p1  = __expf(e1 - m1n);
        l0 = l0 * sc0 + p0;
        l1 = l1 * sc1 + p1;
        float v0 = b2f(xh[src * 128 + lane]);
        float v1 = b2f(xh[src * 128 + 64 + lane]);
        a0 = a0 * sc0 + p0 * v0;
        a1 = a1 * sc1 + p1 * v1;
        m0 = m0n; m1 = m1n;
    }
    float o0 = a0 / fmaxf(l0, 1e-30f) + ldf(b1, lane, f32);
    float o1 = a1 / fmaxf(l1, 1e-30f) + ldf(b1, 64 + lane, f32);
    h1[node * 128 + lane]      = f2b(fmaxf(o0, 0.f));   // relu
    h1[node * 128 + 64 + lane] = f2b(fmaxf(o1, 0.f));
}

// ---------------- layer 2 ----------------
__global__ void k_gemm2(const bf16* __restrict__ h1, const void* __restrict__ W2,
                        const void* __restrict__ a_src, const void* __restrict__ a_dst,
                        const int* __restrict__ flags,
                        bf16* __restrict__ xh2, float* __restrict__ al2) {
    int f32 = flags[0];
    __shared__ float xs[8][128];
    int tid = threadIdx.x;   // 64
    int row0 = blockIdx.x * 8;
    #pragma unroll
    for (int r = 0; r < 8; ++r) {
        xs[r][tid]      = b2f(h1[(row0 + r) * 128 + tid]);
        xs[r][64 + tid] = b2f(h1[(row0 + r) * 128 + 64 + tid]);
    }
    __syncthreads();
    float acc[8] = {0.f,0.f,0.f,0.f,0.f,0.f,0.f,0.f};
    for (int k = 0; k < 128; ++k) {
        float w = ldf(W2, k * 64 + tid, f32);
        #pragma unroll
        for (int r = 0; r < 8; ++r) acc[r] += xs[r][k] * w;
    }
    float asv = ldf(a_src, tid, f32);
    float adv = ldf(a_dst, tid, f32);
    #pragma unroll
    for (int r = 0; r < 8; ++r) {
        int n = row0 + r;
        xh2[n * 64 + tid] = f2b(acc[r]);
        float ps = acc[r] * asv, pd = acc[r] * adv;
        #pragma unroll
        for (int d = 32; d > 0; d >>= 1) {
            ps += __shfl_down(ps, d);
            pd += __shfl_down(pd, d);
        }
        if (tid == 0) { al2[n * 2] = ps; al2[n * 2 + 1] = pd; }
    }
}

__global__ void k_agg2(const bf16* __restrict__ xh2, const float* __restrict__ al2,
                       const void* __restrict__ bias2, const int* __restrict__ flags,
                       const int* __restrict__ off, const int* __restrict__ csr_src,
                       float* __restrict__ h2) {
    int f32 = flags[0];
    int node = blockIdx.x * 4 + threadIdx.y;
    if (node >= N_NODES) return;
    int lane = threadIdx.x;
    float ad = al2[node * 2 + 1];
    int s = off[node], e = off[node + 1];
    float m = -1e30f, l = 0.f, a = 0.f;
    for (int k = s; k < e; ++k) {
        int src = csr_src[k];
        float ev = al2[src * 2] + ad;
        ev = (ev > 0.f) ? ev : 0.2f * ev;
        float mn = fmaxf(m, ev);
        float sc = __expf(m - mn);
        float p  = __expf(ev - mn);
        l = l * sc + p;
        a = a * sc + p * b2f(xh2[src * 64 + lane]);
        m = mn;
    }
    h2[node * 64 + lane] = a / fmaxf(l, 1e-30f) + ldf(bias2, lane, f32);  // no relu
}

// ---------------- pooling + classifier ----------------
__device__ __forceinline__ int lowerb(const void* a, int n, int v, int i64) {
    int lo = 0, hi = n;
    while (lo < hi) { int mid = (lo + hi) >> 1; if (ldi(a, mid, i64) < v) lo = mid + 1; else hi = mid; }
    return lo;
}

__global__ void k_pool(const float* __restrict__ h2, const void* __restrict__ batch,
                       const int* __restrict__ flags, float* __restrict__ ge) {
    int i64 = flags[1];
    int g = blockIdx.x;
    int tid = threadIdx.x;  // 64 = channel
    int s = lowerb(batch, N_NODES, g, i64);
    int e = lowerb(batch, N_NODES, g + 1, i64);
    float acc = 0.f;
    for (int n = s; n < e; ++n) acc += h2[n * 64 + tid];
    ge[g * 64 + tid] = acc;
}

__global__ void k_cls(const float* __restrict__ ge, const void* __restrict__ Wc1,
                      const void* __restrict__ bc1, const void* __restrict__ Wc2,
                      const void* __restrict__ bc2, const void* __restrict__ y,
                      const int* __restrict__ flags, void* __restrict__ out) {
    int f32 = flags[0];
    int i64 = flags[1];
    __shared__ float s[64 * 65];   // +1 pad: kill stride-64 bank conflicts
    int tid = threadIdx.x;         // 64 = graph index
    for (int i = tid; i < 4096; i += 64) {
        float v = ge[i];
        s[(i >> 6) * 65 + (i & 63)] = v;
        if (f32) ((float*)out)[i] = v; else ((bf16*)out)[i] = f2b(v);
    }
    __syncthreads();
    int g = tid;
    float l0 = ldf(bc2, 0, f32), l1 = ldf(bc2, 1, f32);
    for (int j = 0; j < 64; ++j) {
        float h = ldf(bc1, j, f32);
        for (int k = 0; k < 64; ++k) h += s[g * 65 + k] * ldf(Wc1, k * 64 + j, f32);
        h = fmaxf(h, 0.f);
        l0 += h * ldf(Wc2, j * 2, f32);
        l1 += h * ldf(Wc2, j * 2 + 1, f32);
    }
    float mx  = fmaxf(l0, l1);
    float lse = mx + __logf(__expf(l0 - mx) + __expf(l1 - mx));
    float lp0 = l0 - lse, lp1 = l1 - lse;
    float p0 = __expf(lp0), p1 = __expf(lp1);
    int yy = ldi(y, g, i64);
    float loss = -((yy == 0) ? lp0 : lp1);
    int pred = (p1 > p0) ? 1 : 0;        // argmax, first-index tie-break
    int corr = (pred == yy) ? 1 : 0;
    if (f32) {
        ((float*)out)[4098 + g * 2]     = p0;
        ((float*)out)[4098 + g * 2 + 1] = p1;
    } else {
        ((bf16*)out)[4098 + g * 2]     = f2b(p0);
        ((bf16*)out)[4098 + g * 2 + 1] = f2b(p1);
    }
    float ls = loss;
    int cs = corr;
    #pragma unroll
    for (int d = 32; d > 0; d >>= 1) {
        ls += __shfl_down(ls, d);
        cs += __shfl_down(cs, d);
    }
    if (tid == 0) {
        float lv = ls * (1.f / 64.f);
        float cv = (float)cs;
        if (f32) { ((float*)out)[4096] = lv; ((float*)out)[4097] = cv; }
        else     { ((bf16*)out)[4096] = f2b(lv); ((bf16*)out)[4097] = f2b(cv); }
    }
}

extern "C" void kernel_launch(void* const* d_in, const int* in_sizes, int n_in,
                              void* d_out, int out_size, void* d_ws, size_t ws_size,
                              hipStream_t stream) {
    (void)in_sizes; (void)n_in; (void)out_size; (void)ws_size;
    const void* x    = d_in[0];
    const void* ei   = d_in[1];
    const void* batch= d_in[2];
    const void* y    = d_in[3];
    const void* W1   = d_in[4];
    const void* as1  = d_in[5];
    const void* ad1  = d_in[6];
    const void* b1   = d_in[7];
    const void* W2   = d_in[8];
    const void* as2  = d_in[9];
    const void* ad2  = d_in[10];
    const void* b2v  = d_in[11];
    const void* Wc1  = d_in[12];
    const void* bc1  = d_in[13];
    const void* Wc2  = d_in[14];
    const void* bc2  = d_in[15];

    char* p = (char*)d_ws;
    auto alloc = [&](size_t bytes) { char* q = p; p += (bytes + 255) & ~size_t(255); return q; };
    int*   flags = (int*)alloc(8 * sizeof(int));
    int*   off = (int*)  alloc((N_NODES + 1) * sizeof(int));
    int*   cnt = (int*)  alloc(N_NODES * sizeof(int));
    int*   csr = (int*)  alloc((size_t)E_TOT * sizeof(int));
    float* al1 = (float*)alloc((size_t)N_NODES * 4 * sizeof(float));
    float* al2 = (float*)alloc((size_t)N_NODES * 2 * sizeof(float));
    float* ge  = (float*)alloc((size_t)N_GRAPHS * 64 * sizeof(float));
    bf16*  bufA= (bf16*) alloc((size_t)N_NODES * 128 * sizeof(bf16)); // xh1, then xh2
    bf16*  bufB= (bf16*) alloc((size_t)N_NODES * 128 * sizeof(bf16)); // h1, then h2(f32, same bytes)
    bf16*  xh1 = bufA;
    bf16*  h1  = bufB;
    bf16*  xh2 = bufA;                 // xh1 dead after k_agg1
    float* h2  = (float*)bufB;         // h1 dead after k_gemm2; 20000*64 f32 == 20000*128 bf16 bytes

    hipMemsetAsync(cnt, 0, N_NODES * sizeof(int), stream);
    k_detect <<<1, 64, 0, stream>>>(x, ei, flags);
    k_count  <<<(E_TOT + 255) / 256, 256, 0, stream>>>(ei, flags, cnt);
    k_scan   <<<1, 256, 0, stream>>>(cnt, off);
    k_scatter<<<(E_TOT + 255) / 256, 256, 0, stream>>>(ei, flags, off, cnt, csr);
    k_gemm1  <<<N_NODES / 8, 128, 0, stream>>>(x, W1, as1, ad1, flags, xh1, al1);
    k_agg1   <<<N_NODES / 4, dim3(64, 4), 0, stream>>>(xh1, al1, b1, flags, off, csr, h1);
    k_gemm2  <<<N_NODES / 8, 64, 0, stream>>>(h1, W2, as2, ad2, flags, xh2, al2);
    k_agg2   <<<N_NODES / 4, dim3(64, 4), 0, stream>>>(xh2, al2, b2v, flags, off, csr, h2);
    k_pool   <<<N_GRAPHS, 64, 0, stream>>>(h2, batch, flags, ge);
    k_cls    <<<1, 64, 0, stream>>>(ge, Wc1, bc1, Wc2, bc2, y, flags, (void*)d_out);
}

// Round 3
// 349.325 us; speedup vs baseline: 2.3064x; 2.3064x over previous
//
#include <hip/hip_runtime.h>
#include <hip/hip_bf16.h>

#define N_NODES  20000
#define N_EDGES  640000
#define E_TOT    (N_EDGES + N_NODES)
#define N_GRAPHS 64

typedef __hip_bfloat16 bf16;

__device__ __forceinline__ float b2f(bf16 v) { return __bfloat162float(v); }
__device__ __forceinline__ bf16  f2b(float v) { return __float2bfloat16(v); }
__device__ __forceinline__ float lrelu(float x) { return x > 0.f ? x : 0.2f * x; }
// unpack packed bf16 pair (low = even element, high = odd element)
__device__ __forceinline__ float2 bfp2(unsigned u) {
    float2 r;
    r.x = __uint_as_float(u << 16);
    r.y = __uint_as_float(u & 0xffff0000u);
    return r;
}

// dual-dtype loads: flags decided at runtime by k_detect (wave-uniform branch)
__device__ __forceinline__ float ldf(const void* p, int i, int f32) {
    return f32 ? ((const float*)p)[i] : b2f(((const bf16*)p)[i]);
}
__device__ __forceinline__ int ldi(const void* p, int i, int i64) {
    return i64 ? (int)((const long long*)p)[i] : ((const int*)p)[i];
}

// ---------------- dtype sniffing ----------------
__global__ void k_detect(const void* __restrict__ x, const void* __restrict__ ei,
                         int* __restrict__ flags) {
    if (threadIdx.x != 0 || blockIdx.x != 0) return;
    const bf16* xb = (const bf16*)x;
    int f32 = 0;
    for (int i = 0; i < 128; ++i) {
        float v = b2f(xb[i]);
        if (!(fabsf(v) < 1e6f)) f32 = 1;   // catches huge values and NaN
    }
    const int* e32 = (const int*)ei;
    int allzero = 1;
    for (int i = 0; i < 64; ++i) if (e32[2 * i + 1] != 0) allzero = 0;
    flags[0] = f32;
    flags[1] = allzero;
}

// ---------------- CSR build ----------------
__global__ void k_count(const void* __restrict__ ei, const int* __restrict__ flags,
                        int* __restrict__ cnt) {
    int e = blockIdx.x * blockDim.x + threadIdx.x;
    if (e >= E_TOT) return;
    int i64 = flags[1];
    int dst = (e < N_EDGES) ? ldi(ei, N_EDGES + e, i64) : (e - N_EDGES);
    atomicAdd(&cnt[dst], 1);
}

// 1024-thread shuffle scan, 20 elems/thread, 2 barriers
__global__ void k_scan(const int* __restrict__ cnt, int* __restrict__ off) {
    __shared__ int ws[16];
    int tid = threadIdx.x;            // 1024
    int base = tid * 20;
    int c[20];
    int sum = 0;
    #pragma unroll
    for (int i = 0; i < 20; ++i) {
        int idx = base + i;
        int v = (idx < N_NODES) ? cnt[idx] : 0;
        c[i] = v; sum += v;
    }
    int lane = tid & 63, wid = tid >> 6;
    int inc = sum;
    #pragma unroll
    for (int d = 1; d < 64; d <<= 1) { int t = __shfl_up(inc, d); if (lane >= d) inc += t; }
    if (lane == 63) ws[wid] = inc;
    __syncthreads();
    if (wid == 0) {
        int v = (lane < 16) ? ws[lane] : 0;
        #pragma unroll
        for (int d = 1; d < 16; d <<= 1) { int t = __shfl_up(v, d); if (lane >= d) v += t; }
        if (lane < 16) ws[lane] = v;  // inclusive wave sums
    }
    __syncthreads();
    int woff = (wid == 0) ? 0 : ws[wid - 1];
    int run = woff + inc - sum;       // exclusive start for this thread
    #pragma unroll
    for (int i = 0; i < 20; ++i) {
        int idx = base + i;
        if (idx < N_NODES) off[idx] = run;
        run += c[i];
    }
    if (tid == 1023) off[N_NODES] = run;
}

__global__ void k_scatter(const void* __restrict__ ei, const int* __restrict__ flags,
                          const int* __restrict__ off,
                          int* __restrict__ cnt, int* __restrict__ csr_src) {
    int e = blockIdx.x * blockDim.x + threadIdx.x;
    if (e >= E_TOT) return;
    int i64 = flags[1];
    int src, dst;
    if (e < N_EDGES) { src = ldi(ei, e, i64); dst = ldi(ei, N_EDGES + e, i64); }
    else             { src = dst = e - N_EDGES; }
    int r = atomicSub(&cnt[dst], 1);
    csr_src[off[dst] + r - 1] = src;
}

// ---------------- layer 1: x@W1 + attention logits ----------------
// xh1 written HEAD-INTERLEAVED: element (n, ch, head) at n*128 + 2*ch + head
__global__ void k_gemm1(const void* __restrict__ x, const void* __restrict__ W1,
                        const void* __restrict__ a_src, const void* __restrict__ a_dst,
                        const int* __restrict__ flags,
                        bf16* __restrict__ xh, float* __restrict__ al) {
    int f32 = flags[0];
    __shared__ float xs[8][128];
    int tid = threadIdx.x;         // 128
    int row0 = blockIdx.x * 8;
    #pragma unroll
    for (int r = 0; r < 8; ++r) xs[r][tid] = ldf(x, (row0 + r) * 128 + tid, f32);
    __syncthreads();
    float acc[8] = {0.f,0.f,0.f,0.f,0.f,0.f,0.f,0.f};
    for (int k = 0; k < 128; ++k) {
        float w = ldf(W1, k * 128 + tid, f32);
        #pragma unroll
        for (int r = 0; r < 8; ++r) acc[r] += xs[r][k] * w;
    }
    float asv = ldf(a_src, tid, f32);
    float adv = ldf(a_dst, tid, f32);
    int head = tid >> 6, ch = tid & 63;
    #pragma unroll
    for (int r = 0; r < 8; ++r) {
        int n = row0 + r;
        xh[n * 128 + 2 * ch + head] = f2b(acc[r]);
        float ps = acc[r] * asv;
        float pd = acc[r] * adv;
        #pragma unroll
        for (int d = 32; d > 0; d >>= 1) {
            ps += __shfl_down(ps, d);
            pd += __shfl_down(pd, d);
        }
        if ((tid & 63) == 0) {
            al[n * 4 + head]     = ps;   // [as0, as1, ad0, ad1]
            al[n * 4 + 2 + head] = pd;
        }
    }
}

// one wave per dst node; no-max softmax (logits bounded ~|10|), 4x edge unroll
__global__ void k_agg1(const bf16* __restrict__ xh, const float* __restrict__ al,
                       const void* __restrict__ b1, const int* __restrict__ flags,
                       const int* __restrict__ off, const int* __restrict__ csr_src,
                       bf16* __restrict__ h1) {
    int f32 = flags[0];
    int node = blockIdx.x * 4 + threadIdx.y;
    if (node >= N_NODES) return;
    int lane = threadIdx.x;
    float ad0 = al[node * 4 + 2];
    float ad1 = al[node * 4 + 3];
    int s = off[node], e = off[node + 1];
    const unsigned* xhp = (const unsigned*)xh;
    float l0 = 0.f, l1 = 0.f, a0 = 0.f, a1 = 0.f;
    int k = s;
    for (; k + 4 <= e; k += 4) {
        int sA = csr_src[k], sB = csr_src[k+1], sC = csr_src[k+2], sD = csr_src[k+3];
        float2 eA = *(const float2*)(al + sA * 4);
        float2 eB = *(const float2*)(al + sB * 4);
        float2 eC = *(const float2*)(al + sC * 4);
        float2 eD = *(const float2*)(al + sD * 4);
        unsigned vA = xhp[sA * 64 + lane];
        unsigned vB = xhp[sB * 64 + lane];
        unsigned vC = xhp[sC * 64 + lane];
        unsigned vD = xhp[sD * 64 + lane];
        float pA0 = __expf(lrelu(eA.x + ad0)), pA1 = __expf(lrelu(eA.y + ad1));
        float pB0 = __expf(lrelu(eB.x + ad0)), pB1 = __expf(lrelu(eB.y + ad1));
        float pC0 = __expf(lrelu(eC.x + ad0)), pC1 = __expf(lrelu(eC.y + ad1));
        float pD0 = __expf(lrelu(eD.x + ad0)), pD1 = __expf(lrelu(eD.y + ad1));
        float2 fA = bfp2(vA), fB = bfp2(vB), fC = bfp2(vC), fD = bfp2(vD);
        l0 += pA0 + pB0 + pC0 + pD0;
        l1 += pA1 + pB1 + pC1 + pD1;
        a0 += pA0 * fA.x + pB0 * fB.x + pC0 * fC.x + pD0 * fD.x;
        a1 += pA1 * fA.y + pB1 * fB.y + pC1 * fC.y + pD1 * fD.y;
    }
    for (; k < e; ++k) {
        int sA = csr_src[k];
        float2 eA = *(const float2*)(al + sA * 4);
        unsigned vA = xhp[sA * 64 + lane];
        float pA0 = __expf(lrelu(eA.x + ad0)), pA1 = __expf(lrelu(eA.y + ad1));
        float2 fA = bfp2(vA);
        l0 += pA0; l1 += pA1;
        a0 += pA0 * fA.x;
        a1 += pA1 * fA.y;
    }
    float o0 = a0 / l0 + ldf(b1, lane, f32);
    float o1 = a1 / l1 + ldf(b1, 64 + lane, f32);
    h1[node * 128 + lane]      = f2b(fmaxf(o0, 0.f));   // concat order + relu
    h1[node * 128 + 64 + lane] = f2b(fmaxf(o1, 0.f));
}

// ---------------- layer 2 ----------------
__global__ void k_gemm2(const bf16* __restrict__ h1, const void* __restrict__ W2,
                        const void* __restrict__ a_src, const void* __restrict__ a_dst,
                        const int* __restrict__ flags,
                        bf16* __restrict__ xh2, float* __restrict__ al2) {
    int f32 = flags[0];
    __shared__ float xs[8][128];
    int tid = threadIdx.x;   // 64
    int row0 = blockIdx.x * 8;
    #pragma unroll
    for (int r = 0; r < 8; ++r) {
        xs[r][tid]      = b2f(h1[(row0 + r) * 128 + tid]);
        xs[r][64 + tid] = b2f(h1[(row0 + r) * 128 + 64 + tid]);
    }
    __syncthreads();
    float acc[8] = {0.f,0.f,0.f,0.f,0.f,0.f,0.f,0.f};
    for (int k = 0; k < 128; ++k) {
        float w = ldf(W2, k * 64 + tid, f32);
        #pragma unroll
        for (int r = 0; r < 8; ++r) acc[r] += xs[r][k] * w;
    }
    float asv = ldf(a_src, tid, f32);
    float adv = ldf(a_dst, tid, f32);
    #pragma unroll
    for (int r = 0; r < 8; ++r) {
        int n = row0 + r;
        xh2[n * 64 + tid] = f2b(acc[r]);
        float ps = acc[r] * asv, pd = acc[r] * adv;
        #pragma unroll
        for (int d = 32; d > 0; d >>= 1) {
            ps += __shfl_down(ps, d);
            pd += __shfl_down(pd, d);
        }
        if (tid == 0) { al2[n * 2] = ps; al2[n * 2 + 1] = pd; }
    }
}

__global__ void k_agg2(const bf16* __restrict__ xh2, const float* __restrict__ al2,
                       const void* __restrict__ bias2, const int* __restrict__ flags,
                       const int* __restrict__ off, const int* __restrict__ csr_src,
                       float* __restrict__ h2) {
    int f32 = flags[0];
    int node = blockIdx.x * 4 + threadIdx.y;
    if (node >= N_NODES) return;
    int lane = threadIdx.x;
    float ad = al2[node * 2 + 1];
    int s = off[node], e = off[node + 1];
    const unsigned short* xp = (const unsigned short*)xh2;
    float l = 0.f, a = 0.f;
    int k = s;
    for (; k + 4 <= e; k += 4) {
        int sA = csr_src[k], sB = csr_src[k+1], sC = csr_src[k+2], sD = csr_src[k+3];
        float eA = al2[sA * 2], eB = al2[sB * 2], eC = al2[sC * 2], eD = al2[sD * 2];
        unsigned short vA = xp[sA * 64 + lane];
        unsigned short vB = xp[sB * 64 + lane];
        unsigned short vC = xp[sC * 64 + lane];
        unsigned short vD = xp[sD * 64 + lane];
        float pA = __expf(lrelu(eA + ad));
        float pB = __expf(lrelu(eB + ad));
        float pC = __expf(lrelu(eC + ad));
        float pD = __expf(lrelu(eD + ad));
        l += pA + pB + pC + pD;
        a += pA * __uint_as_float((unsigned)vA << 16)
           + pB * __uint_as_float((unsigned)vB << 16)
           + pC * __uint_as_float((unsigned)vC << 16)
           + pD * __uint_as_float((unsigned)vD << 16);
    }
    for (; k < e; ++k) {
        int sA = csr_src[k];
        float eA = al2[sA * 2];
        unsigned short vA = xp[sA * 64 + lane];
        float pA = __expf(lrelu(eA + ad));
        l += pA;
        a += pA * __uint_as_float((unsigned)vA << 16);
    }
    h2[node * 64 + lane] = a / l + ldf(bias2, lane, f32);  // no relu
}

// ---------------- pooling + classifier ----------------
__device__ __forceinline__ int lowerb(const void* a, int n, int v, int i64) {
    int lo = 0, hi = n;
    while (lo < hi) { int mid = (lo + hi) >> 1; if (ldi(a, mid, i64) < v) lo = mid + 1; else hi = mid; }
    return lo;
}

__global__ void k_pool(const float* __restrict__ h2, const void* __restrict__ batch,
                       const int* __restrict__ flags, float* __restrict__ ge) {
    __shared__ float part[4][64];
    int i64 = flags[1];
    int g = blockIdx.x;
    int tid = threadIdx.x;  // channel
    int ty  = threadIdx.y;  // 4 row-chunks
    int s = lowerb(batch, N_NODES, g, i64);
    int e = lowerb(batch, N_NODES, g + 1, i64);
    float acc = 0.f;
    for (int n = s + ty; n < e; n += 4) acc += h2[n * 64 + tid];
    part[ty][tid] = acc;
    __syncthreads();
    if (ty == 0) ge[g * 64 + tid] = part[0][tid] + part[1][tid] + part[2][tid] + part[3][tid];
}

__global__ void k_cls(const float* __restrict__ ge, const void* __restrict__ Wc1,
                      const void* __restrict__ bc1, const void* __restrict__ Wc2,
                      const void* __restrict__ bc2, const void* __restrict__ y,
                      const int* __restrict__ flags, void* __restrict__ out) {
    int f32 = flags[0];
    int i64 = flags[1];
    __shared__ float sge[64 * 65];     // padded
    __shared__ float sw1[4096];
    __shared__ float sw2[128];
    __shared__ float sb1[64];
    __shared__ float part0[4][64], part1[4][64];
    int tid = threadIdx.x;             // 256
    for (int i = tid; i < 4096; i += 256) {
        float v = ge[i];
        sge[(i >> 6) * 65 + (i & 63)] = v;
        if (f32) ((float*)out)[i] = v; else ((bf16*)out)[i] = f2b(v);
    }
    for (int i = tid; i < 4096; i += 256) sw1[i] = ldf(Wc1, i, f32);
    if (tid < 128) sw2[tid] = ldf(Wc2, tid, f32);
    if (tid < 64)  sb1[tid] = ldf(bc1, tid, f32);
    __syncthreads();
    int g = tid & 63, jq = tid >> 6;
    float p0 = 0.f, p1 = 0.f;
    for (int j = jq * 16; j < jq * 16 + 16; ++j) {
        float h = sb1[j];
        #pragma unroll 4
        for (int kk = 0; kk < 64; ++kk) h += sge[g * 65 + kk] * sw1[kk * 64 + j];
        h = fmaxf(h, 0.f);
        p0 += h * sw2[2 * j];
        p1 += h * sw2[2 * j + 1];
    }
    part0[jq][g] = p0; part1[jq][g] = p1;
    __syncthreads();
    if (tid < 64) {
        float l0 = ldf(bc2, 0, f32) + part0[0][g] + part0[1][g] + part0[2][g] + part0[3][g];
        float l1 = ldf(bc2, 1, f32) + part1[0][g] + part1[1][g] + part1[2][g] + part1[3][g];
        float mx  = fmaxf(l0, l1);
        float lse = mx + __logf(__expf(l0 - mx) + __expf(l1 - mx));
        float lp0 = l0 - lse, lp1 = l1 - lse;
        float q0 = __expf(lp0), q1 = __expf(lp1);
        int yy = ldi(y, g, i64);
        float loss = -((yy == 0) ? lp0 : lp1);
        int pred = (q1 > q0) ? 1 : 0;
        int corr = (pred == yy) ? 1 : 0;
        if (f32) {
            ((float*)out)[4098 + g * 2]     = q0;
            ((float*)out)[4098 + g * 2 + 1] = q1;
        } else {
            ((bf16*)out)[4098 + g * 2]     = f2b(q0);
            ((bf16*)out)[4098 + g * 2 + 1] = f2b(q1);
        }
        float ls = loss;
        int cs = corr;
        #pragma unroll
        for (int d = 32; d > 0; d >>= 1) {
            ls += __shfl_down(ls, d);
            cs += __shfl_down(cs, d);
        }
        if (g == 0) {
            float lv = ls * (1.f / 64.f);
            float cv = (float)cs;
            if (f32) { ((float*)out)[4096] = lv; ((float*)out)[4097] = cv; }
            else     { ((bf16*)out)[4096] = f2b(lv); ((bf16*)out)[4097] = f2b(cv); }
        }
    }
}

extern "C" void kernel_launch(void* const* d_in, const int* in_sizes, int n_in,
                              void* d_out, int out_size, void* d_ws, size_t ws_size,
                              hipStream_t stream) {
    (void)in_sizes; (void)n_in; (void)out_size; (void)ws_size;
    const void* x    = d_in[0];
    const void* ei   = d_in[1];
    const void* batch= d_in[2];
    const void* y    = d_in[3];
    const void* W1   = d_in[4];
    const void* as1  = d_in[5];
    const void* ad1  = d_in[6];
    const void* b1   = d_in[7];
    const void* W2   = d_in[8];
    const void* as2  = d_in[9];
    const void* ad2  = d_in[10];
    const void* b2v  = d_in[11];
    const void* Wc1  = d_in[12];
    const void* bc1  = d_in[13];
    const void* Wc2  = d_in[14];
    const void* bc2  = d_in[15];

    char* p = (char*)d_ws;
    auto alloc = [&](size_t bytes) { char* q = p; p += (bytes + 255) & ~size_t(255); return q; };
    int*   flags = (int*)alloc(8 * sizeof(int));
    int*   off = (int*)  alloc((N_NODES + 1) * sizeof(int));
    int*   cnt = (int*)  alloc(N_NODES * sizeof(int));
    int*   csr = (int*)  alloc((size_t)E_TOT * sizeof(int));
    float* al1 = (float*)alloc((size_t)N_NODES * 4 * sizeof(float));
    float* al2 = (float*)alloc((size_t)N_NODES * 2 * sizeof(float));
    float* ge  = (float*)alloc((size_t)N_GRAPHS * 64 * sizeof(float));
    bf16*  bufA= (bf16*) alloc((size_t)N_NODES * 128 * sizeof(bf16));
    bf16*  bufB= (bf16*) alloc((size_t)N_NODES * 128 * sizeof(bf16));
    bf16*  xh1 = bufA;                 // head-interleaved
    bf16*  h1  = bufB;                 // concat order
    bf16*  xh2 = bufA;                 // reuse: xh1 dead after k_agg1
    float* h2  = (float*)bufB;         // reuse: h1 dead after k_gemm2

    hipMemsetAsync(cnt, 0, N_NODES * sizeof(int), stream);
    k_detect <<<1, 64, 0, stream>>>(x, ei, flags);
    k_count  <<<(E_TOT + 255) / 256, 256, 0, stream>>>(ei, flags, cnt);
    k_scan   <<<1, 1024, 0, stream>>>(cnt, off);
    k_scatter<<<(E_TOT + 255) / 256, 256, 0, stream>>>(ei, flags, off, cnt, csr);
    k_gemm1  <<<N_NODES / 8, 128, 0, stream>>>(x, W1, as1, ad1, flags, xh1, al1);
    k_agg1   <<<N_NODES / 4, dim3(64, 4), 0, stream>>>(xh1, al1, b1, flags, off, csr, h1);
    k_gemm2  <<<N_NODES / 8, 64, 0, stream>>>(h1, W2, as2, ad2, flags, xh2, al2);
    k_agg2   <<<N_NODES / 4, dim3(64, 4), 0, stream>>>(xh2, al2, b2v, flags, off, csr, h2);
    k_pool   <<<N_GRAPHS, dim3(64, 4), 0, stream>>>(h2, batch, flags, ge);
    k_cls    <<<1, 256, 0, stream>>>(ge, Wc1, bc1, Wc2, bc2, y, flags, (void*)d_out);
}